// Round 12
// baseline (320.754 us; speedup 1.0000x reference)
//
#include <hip/hip_runtime.h>
#include <hip/hip_bf16.h>
#include <hip/hip_fp16.h>

// DeepSetPred R12 = R11 with two bug fixes (structure unchanged):
//  (1) bias: init_acc reads b1s/b2s/b3 DIRECTLY from global (R11 read sbias
//      LDS written by tid<256 with no barrier -> race, waves 4-7 got garbage).
//  (2) workspace: h1/h2 are 128MB each (131072x512x2B); R11 placed h2 at
//      h1+64MB -> enc2 output clobbered h1's upper half. Total need 269.6MB,
//      proven to fit by R7's unfused run.
// Structure: unfused 3-GEMM, 256x256 tiles, fragment-ordered operands so all
// in-loop LDS ops are linear lane*16 b128 (conflict-free). 1 vmcnt(0)+barrier
// per K-step; staging of s+1 overlaps compute(s). 8 waves = 4 wf x 2 wt,
// acc 2x4 f32x16 (128 AGPR). 32x32x16 MFMA.

typedef _Float16 half8v __attribute__((ext_vector_type(8)));
typedef _Float16 half4v __attribute__((ext_vector_type(4)));
typedef float f32x4 __attribute__((ext_vector_type(4)));
typedef float f32x16 __attribute__((ext_vector_type(16)));

#define TANH_SCALE 2.8853900817779268f  // 2*log2(e)

__device__ __forceinline__ void gload_lds16(const void* g, void* l) {
    __builtin_amdgcn_global_load_lds(
        (const __attribute__((address_space(1))) void*)g,
        (__attribute__((address_space(3))) void*)l, 16, 0, 0);
}
__device__ __forceinline__ void vm0_bar() {
    asm volatile("s_waitcnt vmcnt(0)" ::: "memory");
    __builtin_amdgcn_s_barrier();
    __builtin_amdgcn_sched_barrier(0);
}
__device__ __forceinline__ void lgkm0_bar() {
    asm volatile("s_waitcnt lgkmcnt(0)" ::: "memory");
    __builtin_amdgcn_s_barrier();
    __builtin_amdgcn_sched_barrier(0);
}
__device__ __forceinline__ float tanh_half(float x) {  // x pre-scaled by 2log2e
    float e = __builtin_amdgcn_exp2f(x);
    float r = __builtin_amdgcn_rcpf(e + 1.0f);
    return fmaf(-2.0f, r, 1.0f);
}

// ---------------- weight fragmentizer ----------------
// Frag-lane unit u (16B): layer layout [p][s][kc(4)][ftile(8)][lane(64)][8 halfs]
// L1: u 0..16383 (P2,NS4); L2: 16384..49151 (P2,NS8); L3: 49152..65535 (P1,NS8)
__global__ __launch_bounds__(256) void wt_kernel(
    const float* __restrict__ W1, const float* __restrict__ W2,
    const float* __restrict__ W3, const float* __restrict__ b1,
    const float* __restrict__ b2,
    _Float16* __restrict__ F1, _Float16* __restrict__ F2,
    _Float16* __restrict__ F3, float* __restrict__ b1s, float* __restrict__ b2s) {
    int u = blockIdx.x * 256 + threadIdx.x;
    if (u < 512) b1s[u] = b1[u] * TANH_SCALE;
    else if (u < 1024) b2s[u - 512] = b2[u - 512] * TANH_SCALE;

    const float* W; _Float16* F; int FW, NS, u0; float scale;
    if (u < 16384)      { W = W1; F = F1; FW = 512; NS = 4; u0 = u;          scale = TANH_SCALE; }
    else if (u < 49152) { W = W2; F = F2; FW = 512; NS = 8; u0 = u - 16384;  scale = TANH_SCALE; }
    else                { W = W3; F = F3; FW = 256; NS = 8; u0 = u - 49152;  scale = 1.0f; }
    int lane = u0 & 63;
    int fi = u0 >> 6;
    int ftile = fi & 7, kc = (fi >> 3) & 3;
    int si = fi >> 5;
    int s = si % NS, p = si / NS;
    int f = p * 256 + ftile * 32 + (lane & 31);
    int k0 = s * 64 + kc * 16 + (lane >> 5) * 8;
    half8v v;
    #pragma unroll
    for (int j = 0; j < 8; ++j)
        v[j] = (_Float16)(W[(size_t)(k0 + j) * FW + f] * scale);
    *(half8v*)((char*)F + (size_t)u0 * 16) = v;
}

// ---------------- shared compute: one K-step (64k) ----------------
// wb/ab: 32KB frag tiles: frag(kc*8 + idx), byte = frag*1024 + lane*16.
__device__ __forceinline__ void kstep_compute(const char* wb, const char* ab,
                                              int wf, int wt, int lane,
                                              f32x16 acc[2][4]) {
    #pragma unroll
    for (int kc = 0; kc < 4; ++kc) {
        half8v A0 = *(const half8v*)(wb + (kc * 8 + wf * 2 + 0) * 1024 + lane * 16);
        half8v A1 = *(const half8v*)(wb + (kc * 8 + wf * 2 + 1) * 1024 + lane * 16);
        #pragma unroll
        for (int nt = 0; nt < 4; ++nt) {
            half8v B = *(const half8v*)(ab + (kc * 8 + wt * 4 + nt) * 1024 + lane * 16);
            acc[0][nt] = __builtin_amdgcn_mfma_f32_32x32x16_f16(A0, B, acc[0][nt], 0, 0, 0);
            acc[1][nt] = __builtin_amdgcn_mfma_f32_32x32x16_f16(A1, B, acc[1][nt], 0, 0, 0);
        }
    }
}

// bias from GLOBAL (fix #1): lane reads its own 8 f32x4 slices (L2-resident)
__device__ __forceinline__ void init_acc(f32x16 acc[2][4], const float* bias,
                                         int wf, int hi) {
    #pragma unroll
    for (int mt = 0; mt < 2; ++mt) {
        #pragma unroll
        for (int q = 0; q < 4; ++q) {
            f32x4 bv = *(const f32x4*)(bias + wf * 64 + mt * 32 + q * 8 + hi * 4);
            #pragma unroll
            for (int nt = 0; nt < 4; ++nt)
                #pragma unroll
                for (int j = 0; j < 4; ++j) acc[mt][nt][q * 4 + j] = bv[j];
        }
    }
}

// epilogue for L1/L2: acc -> tanh fp16 image [256 t][512B] (XOR swz) -> h frags
__device__ __forceinline__ void epi_h(char* smem, const f32x16 acc[2][4],
                                      _Float16* __restrict__ h, int Tt, int p,
                                      int wave, int wf, int wt, int lane,
                                      int r2, int hi) {
    #pragma unroll
    for (int mt = 0; mt < 2; ++mt)
        #pragma unroll
        for (int nt = 0; nt < 4; ++nt) {
            int t = wt * 128 + nt * 32 + r2;
            #pragma unroll
            for (int q = 0; q < 4; ++q) {
                int floc = wf * 64 + mt * 32 + q * 8 + hi * 4;
                half4v hv;
                #pragma unroll
                for (int j = 0; j < 4; ++j)
                    hv[j] = (_Float16)tanh_half(acc[mt][nt][q * 4 + j]);
                *(half4v*)(smem + t * 512 + ((floc * 2) ^ ((t & 7) << 4))) = hv;
            }
        }
    lgkm0_bar();
    #pragma unroll
    for (int r = 0; r < 16; ++r) {
        int fid = wave * 16 + r;
        int fs = fid >> 5, kcp = (fid >> 3) & 3, tt = fid & 7;
        int t = tt * 32 + (lane & 31);
        int chunk = fs * 128 + kcp * 32 + (lane >> 5) * 16;
        uint4 v = *(const uint4*)(smem + t * 512 + (chunk ^ ((t & 7) << 4)));
        char* dst = (char*)h + (((size_t)(p * 4 + fs) * 512 + Tt) * 32 + kcp * 8 + tt) * 1024
                    + lane * 16;
        *(uint4*)dst = v;
    }
}

// ---------------- L1: words (fp32, reg-staged) ----------------
__global__ __launch_bounds__(512, 2) void enc1_kernel(
    const float* __restrict__ words, const _Float16* __restrict__ F1,
    const float* __restrict__ b1s, _Float16* __restrict__ h1) {
    __shared__ __align__(16) char smem[131072];   // wbuf 2x32K @0 | abuf 2x32K @65536

    const int tid = threadIdx.x;
    const int lane = tid & 63, wave = tid >> 6;
    const int r2 = lane & 31, hi = lane >> 5;
    const int wf = wave >> 1, wt = wave & 1;
    const int Tt = blockIdx.x >> 1, p = blockIdx.x & 1;

    const char* Fbase = (const char*)F1 + (size_t)p * 4 * 32768;
    auto stage_w = [&](int s) {
        const char* g = Fbase + (size_t)s * 32768;
        char* l = smem + (s & 1) * 32768;
        #pragma unroll
        for (int it = 0; it < 4; ++it) {
            int o = (it * 512 + tid) * 16;
            gload_lds16(g + o, l + o);
        }
    };
    // words tile [256 t][64 k] fp32: thread (t=tid>>1, kh=tid&1) owns 32 floats
    const int t_l = tid >> 1, kh = tid & 1;
    const float* wrow = words + ((size_t)Tt * 256 + t_l) * 256 + kh * 32;
    float4 g[8];
    auto load_g = [&](int s) {
        const float4* src = (const float4*)(wrow + s * 64);
        #pragma unroll
        for (int c = 0; c < 8; ++c) g[c] = src[c];
    };
    auto write_g = [&](int s) {
        char* ab = smem + 65536 + (s & 1) * 32768;
        #pragma unroll
        for (int g2 = 0; g2 < 4; ++g2) {        // 8 floats -> one frag-lane 16B
            int kc = kh * 2 + (g2 >> 1);
            int h2 = g2 & 1;
            half8v hv;
            hv[0] = (_Float16)g[2 * g2].x;     hv[1] = (_Float16)g[2 * g2].y;
            hv[2] = (_Float16)g[2 * g2].z;     hv[3] = (_Float16)g[2 * g2].w;
            hv[4] = (_Float16)g[2 * g2 + 1].x; hv[5] = (_Float16)g[2 * g2 + 1].y;
            hv[6] = (_Float16)g[2 * g2 + 1].z; hv[7] = (_Float16)g[2 * g2 + 1].w;
            *(half8v*)(ab + (kc * 8 + (t_l >> 5)) * 1024 + ((t_l & 31) + 32 * h2) * 16) = hv;
        }
    };

    f32x16 acc[2][4];
    init_acc(acc, b1s + p * 256, wf, hi);

    // prologue: tile 0
    stage_w(0);
    load_g(0);
    asm volatile("s_waitcnt vmcnt(0)" ::: "memory");
    write_g(0);
    lgkm0_bar();

    #pragma unroll
    for (int s = 0; s < 4; ++s) {
        if (s < 3) { stage_w(s + 1); load_g(s + 1); }
        kstep_compute(smem + (s & 1) * 32768, smem + 65536 + (s & 1) * 32768,
                      wf, wt, lane, acc);
        if (s < 3) {
            vm0_bar();            // W(s+1),g(s+1) landed; everyone's reads of s-1 bufs retired
            write_g(s + 1);
            lgkm0_bar();          // act(s+1) visible
        }
    }
    __builtin_amdgcn_s_barrier();  // all compute reads retired -> reuse smem
    epi_h(smem, acc, h1, Tt, p, wave, wf, wt, lane, r2, hi);
}

// ---------------- L2: h1 (frag-gloaded) ----------------
__global__ __launch_bounds__(512, 2) void enc2_kernel(
    const _Float16* __restrict__ h1, const _Float16* __restrict__ F2,
    const float* __restrict__ b2s, _Float16* __restrict__ h2) {
    __shared__ __align__(16) char smem[131072];

    const int tid = threadIdx.x;
    const int lane = tid & 63, wave = tid >> 6;
    const int r2 = lane & 31, hi = lane >> 5;
    const int wf = wave >> 1, wt = wave & 1;
    const int Tt = blockIdx.x >> 1, p = blockIdx.x & 1;

    const char* Fbase = (const char*)F2 + (size_t)p * 8 * 32768;
    auto stage = [&](int s) {
        const char* gw = Fbase + (size_t)s * 32768;
        const char* ga = (const char*)h1 + ((size_t)s * 512 + Tt) * 32768;
        char* lw = smem + (s & 1) * 32768;
        char* la = smem + 65536 + (s & 1) * 32768;
        #pragma unroll
        for (int it = 0; it < 4; ++it) {
            int o = (it * 512 + tid) * 16;
            gload_lds16(gw + o, lw + o);
        }
        #pragma unroll
        for (int it = 0; it < 4; ++it) {
            int o = (it * 512 + tid) * 16;
            gload_lds16(ga + o, la + o);
        }
    };

    f32x16 acc[2][4];
    init_acc(acc, b2s + p * 256, wf, hi);

    stage(0);
    #pragma unroll
    for (int s = 0; s < 8; ++s) {
        vm0_bar();                 // tile(s) ready; prev readers done
        if (s < 7) stage(s + 1);
        kstep_compute(smem + (s & 1) * 32768, smem + 65536 + (s & 1) * 32768,
                      wf, wt, lane, acc);
    }
    __builtin_amdgcn_s_barrier();
    epi_h(smem, acc, h2, Tt, p, wave, wf, wt, lane, r2, hi);
}

// ---------------- L3: h2 -> enc (fused segment sum) ----------------
__global__ __launch_bounds__(512, 2) void enc3_kernel(
    const _Float16* __restrict__ h2, const _Float16* __restrict__ F3,
    const float* __restrict__ b3, const int* __restrict__ seg_ids,
    float* __restrict__ enc) {
    __shared__ __align__(16) char smem[132096];   // staging 128K; epi image [128t][1032B]
    __shared__ int sseg[256];

    const int tid = threadIdx.x;
    const int lane = tid & 63, wave = tid >> 6;
    const int r2 = lane & 31, hi = lane >> 5;
    const int wf = wave >> 1, wt = wave & 1;
    const int Tt = blockIdx.x;

    if (tid < 256) sseg[tid] = seg_ids[Tt * 256 + tid];   // first read is after
                                                          // many barriers below
    auto stage = [&](int s) {
        const char* gw = (const char*)F3 + (size_t)s * 32768;
        const char* ga = (const char*)h2 + ((size_t)s * 512 + Tt) * 32768;
        char* lw = smem + (s & 1) * 32768;
        char* la = smem + 65536 + (s & 1) * 32768;
        #pragma unroll
        for (int it = 0; it < 4; ++it) {
            int o = (it * 512 + tid) * 16;
            gload_lds16(gw + o, lw + o);
        }
        #pragma unroll
        for (int it = 0; it < 4; ++it) {
            int o = (it * 512 + tid) * 16;
            gload_lds16(ga + o, la + o);
        }
    };

    f32x16 acc[2][4];
    init_acc(acc, b3, wf, hi);

    stage(0);
    #pragma unroll
    for (int s = 0; s < 8; ++s) {
        vm0_bar();
        if (s < 7) stage(s + 1);
        kstep_compute(smem + (s & 1) * 32768, smem + 65536 + (s & 1) * 32768,
                      wf, wt, lane, acc);
    }
    __builtin_amdgcn_s_barrier();

    // segment sum in 2 t-half rounds via image [128 tl][1032 B] (f32, t-major)
    #pragma unroll
    for (int th = 0; th < 2; ++th) {
        if (wt == th) {
            #pragma unroll
            for (int mt = 0; mt < 2; ++mt)
                #pragma unroll
                for (int nt = 0; nt < 4; ++nt) {
                    int tl = nt * 32 + r2;
                    #pragma unroll
                    for (int q = 0; q < 4; ++q) {
                        int floc = wf * 64 + mt * 32 + q * 8 + hi * 4;
                        *(float2*)(smem + tl * 1032 + floc * 4) =
                            make_float2(acc[mt][nt][q * 4 + 0], acc[mt][nt][q * 4 + 1]);
                        *(float2*)(smem + tl * 1032 + (floc + 2) * 4) =
                            make_float2(acc[mt][nt][q * 4 + 2], acc[mt][nt][q * 4 + 3]);
                    }
                }
        }
        lgkm0_bar();
        {
            int f = tid >> 1, tsub = tid & 1;
            float a = 0.0f;
            int cur = sseg[th * 128 + tsub * 64];
            for (int i = 0; i < 64; ++i) {
                int tl = tsub * 64 + i;
                float v = *(const float*)(smem + tl * 1032 + f * 4);
                int sg = sseg[th * 128 + tl];
                if (sg != cur) { atomicAdd(&enc[cur * 256 + f], a); a = 0.0f; cur = sg; }
                a += v;
            }
            atomicAdd(&enc[cur * 256 + f], a);
        }
        __builtin_amdgcn_s_barrier();
    }
}

// ---------------- predictor (tiny, fp32) ----------------
__global__ __launch_bounds__(256) void pred_kernel(
    const float* __restrict__ enc,
    const float* __restrict__ P1, const float* __restrict__ pb1,
    const float* __restrict__ P2, const float* __restrict__ pb2,
    const float* __restrict__ P3, const float* __restrict__ pb3,
    float* __restrict__ out) {
    __shared__ float se[256];
    __shared__ float sp[512];
    __shared__ float red[256];
    const int tid = threadIdx.x, b = blockIdx.x;
    se[tid] = enc[b * 256 + tid];
    __syncthreads();
    float a0 = pb1[tid], a1 = pb1[tid + 256];
    for (int k = 0; k < 256; ++k) {
        float e = se[k];
        a0 = fmaf(e, P1[k * 512 + tid], a0);
        a1 = fmaf(e, P1[k * 512 + tid + 256], a1);
    }
    sp[tid] = tanhf(a0);
    sp[tid + 256] = tanhf(a1);
    __syncthreads();
    a0 = pb2[tid]; a1 = pb2[tid + 256];
    for (int k = 0; k < 512; ++k) {
        float p = sp[k];
        a0 = fmaf(p, P2[k * 512 + tid], a0);
        a1 = fmaf(p, P2[k * 512 + tid + 256], a1);
    }
    __syncthreads();
    sp[tid] = tanhf(a0);
    sp[tid + 256] = tanhf(a1);
    __syncthreads();
    int j = tid & 31, part = tid >> 5;
    float s = 0.0f;
    for (int k = part * 64; k < part * 64 + 64; ++k)
        s = fmaf(sp[k], P3[k * 32 + j], s);
    red[tid] = s;
    __syncthreads();
    if (tid < 128) red[tid] += red[tid + 128];
    __syncthreads();
    if (tid < 64) red[tid] += red[tid + 64];
    __syncthreads();
    if (tid < 32) out[b * 32 + tid] = red[tid] + red[tid + 32] + pb3[tid];
}

extern "C" void kernel_launch(void* const* d_in, const int* in_sizes, int n_in,
                              void* d_out, int out_size, void* d_ws, size_t ws_size,
                              hipStream_t stream) {
    const float* words = (const float*)d_in[0];
    const int* seg_ids = (const int*)d_in[1];
    const float* W1 = (const float*)d_in[2];
    const float* b1 = (const float*)d_in[3];
    const float* W2 = (const float*)d_in[4];
    const float* b2 = (const float*)d_in[5];
    const float* W3 = (const float*)d_in[6];
    const float* b3 = (const float*)d_in[7];
    const float* P1 = (const float*)d_in[8];
    const float* pb1 = (const float*)d_in[9];
    const float* P2 = (const float*)d_in[10];
    const float* pb2 = (const float*)d_in[11];
    const float* P3 = (const float*)d_in[12];
    const float* pb3 = (const float*)d_in[13];
    float* out = (float*)d_out;

    char* ws = (char*)d_ws;
    _Float16* F1 = (_Float16*)(ws);                  // 262144 B
    _Float16* F2 = (_Float16*)(ws + 262144);         // 524288 B
    _Float16* F3 = (_Float16*)(ws + 786432);         // 262144 B
    float* b1s = (float*)(ws + 1048576);             // 2048 B
    float* b2s = (float*)(ws + 1050624);             // 2048 B
    float* enc = (float*)(ws + 1052672);             // 131072 B
    _Float16* h1 = (_Float16*)(ws + 1183744);        // 134217728 B (fix #2)
    _Float16* h2 = (_Float16*)(ws + 135401472);      // 134217728 B (fix #2)

    hipMemsetAsync(enc, 0, 128 * 256 * 4, stream);
    wt_kernel<<<256, 256, 0, stream>>>(W1, W2, W3, b1, b2, F1, F2, F3, b1s, b2s);
    enc1_kernel<<<1024, 512, 0, stream>>>(words, F1, b1s, h1);
    enc2_kernel<<<1024, 512, 0, stream>>>(h1, F2, b2s, h2);
    enc3_kernel<<<512, 512, 0, stream>>>(h2, F3, b3, seg_ids, enc);
    pred_kernel<<<128, 256, 0, stream>>>(enc, P1, pb1, P2, pb2, P3, pb3, out);
}

// Round 13
// 304.084 us; speedup vs baseline: 1.0548x; 1.0548x over previous
//
#include <hip/hip_runtime.h>
#include <hip/hip_bf16.h>
#include <hip/hip_fp16.h>

// DeepSetPred R13: R12 structure re-tiled for 2 blocks/CU + XCD locality.
//  - tile 256t x 128f (acc 64 AGPR/wave), K-step 32: staging 48KB dbuf,
//    block LDS 65-67KB -> 2 blocks/CU (R12: 128KB, 1 block/CU, 2.2TB/s).
//  - XCD-grouped mapping: sibling p-blocks of one act tile co-run on one XCD
//    -> duplicate act reads are L2 hits, not HBM.
//  - frag unit 1KB (64 lanes x 16B); W tile/step = 8KB, act tile/step = 16KB.
// Pipeline/sync protocol identical to R12 (vmcnt(0)+barrier per step).

typedef _Float16 half8v __attribute__((ext_vector_type(8)));
typedef _Float16 half4v __attribute__((ext_vector_type(4)));
typedef float f32x4 __attribute__((ext_vector_type(4)));
typedef float f32x16 __attribute__((ext_vector_type(16)));

#define TANH_SCALE 2.8853900817779268f  // 2*log2(e)

__device__ __forceinline__ void gload_lds16(const void* g, void* l) {
    __builtin_amdgcn_global_load_lds(
        (const __attribute__((address_space(1))) void*)g,
        (__attribute__((address_space(3))) void*)l, 16, 0, 0);
}
__device__ __forceinline__ void vm0_bar() {
    asm volatile("s_waitcnt vmcnt(0)" ::: "memory");
    __builtin_amdgcn_s_barrier();
    __builtin_amdgcn_sched_barrier(0);
}
__device__ __forceinline__ void lgkm0_bar() {
    asm volatile("s_waitcnt lgkmcnt(0)" ::: "memory");
    __builtin_amdgcn_s_barrier();
    __builtin_amdgcn_sched_barrier(0);
}
__device__ __forceinline__ float tanh_half(float x) {  // x pre-scaled by 2log2e
    float e = __builtin_amdgcn_exp2f(x);
    float r = __builtin_amdgcn_rcpf(e + 1.0f);
    return fmaf(-2.0f, r, 1.0f);
}

// ---------------- weight fragmentizer ----------------
// Frag unit u (16B/lane): layer layout [p][s][kc(2)][ft(4)][lane(64)][8 halfs]
// L1: 16384 units (P4,NS8) | L2: 32768 (P4,NS16) | L3: 16384 (P2,NS16)
__global__ __launch_bounds__(256) void wt_kernel(
    const float* __restrict__ W1, const float* __restrict__ W2,
    const float* __restrict__ W3, const float* __restrict__ b1,
    const float* __restrict__ b2,
    _Float16* __restrict__ F1, _Float16* __restrict__ F2,
    _Float16* __restrict__ F3, float* __restrict__ b1s, float* __restrict__ b2s) {
    int u = blockIdx.x * 256 + threadIdx.x;   // 0..65535
    if (u < 512) b1s[u] = b1[u] * TANH_SCALE;
    else if (u < 1024) b2s[u - 512] = b2[u - 512] * TANH_SCALE;

    const float* W; _Float16* F; int FW, NS, u0; float scale;
    if (u < 16384)      { W = W1; F = F1; FW = 512; NS = 8;  u0 = u;         scale = TANH_SCALE; }
    else if (u < 49152) { W = W2; F = F2; FW = 512; NS = 16; u0 = u - 16384; scale = TANH_SCALE; }
    else                { W = W3; F = F3; FW = 256; NS = 16; u0 = u - 49152; scale = 1.0f; }
    int lane = u0 & 63;
    int g = u0 >> 6;
    int ft = g & 3, kc = (g >> 2) & 1;
    int sp = g >> 3;
    int s = sp % NS, p = sp / NS;
    int f = p * 128 + ft * 32 + (lane & 31);
    int k0 = s * 32 + kc * 16 + (lane >> 5) * 8;
    half8v v;
    #pragma unroll
    for (int j = 0; j < 8; ++j)
        v[j] = (_Float16)(W[(size_t)(k0 + j) * FW + f] * scale);
    *(half8v*)((char*)F + (size_t)u0 * 16) = v;
}

// ---------------- shared pieces ----------------
// one K-step(32): wb = 8KB [kc2][ft4], ab = 16KB [kc2][tt8]; 8 MFMA/wave
__device__ __forceinline__ void kstep_compute(const char* wb, const char* ab,
                                              int wf, int wt, int lane,
                                              f32x16 acc[2][2]) {
    #pragma unroll
    for (int kc = 0; kc < 2; ++kc) {
        half8v A0 = *(const half8v*)(wb + (kc * 4 + wf * 2 + 0) * 1024 + lane * 16);
        half8v A1 = *(const half8v*)(wb + (kc * 4 + wf * 2 + 1) * 1024 + lane * 16);
        #pragma unroll
        for (int nt = 0; nt < 2; ++nt) {
            half8v B = *(const half8v*)(ab + (kc * 8 + wt * 2 + nt) * 1024 + lane * 16);
            acc[0][nt] = __builtin_amdgcn_mfma_f32_32x32x16_f16(A0, B, acc[0][nt], 0, 0, 0);
            acc[1][nt] = __builtin_amdgcn_mfma_f32_32x32x16_f16(A1, B, acc[1][nt], 0, 0, 0);
        }
    }
}

__device__ __forceinline__ void init_acc(f32x16 acc[2][2], const float* bias,
                                         int wf, int hi) {
    #pragma unroll
    for (int mt = 0; mt < 2; ++mt)
        #pragma unroll
        for (int q = 0; q < 4; ++q) {
            f32x4 bv = *(const f32x4*)(bias + wf * 64 + mt * 32 + q * 8 + hi * 4);
            #pragma unroll
            for (int nt = 0; nt < 2; ++nt)
                #pragma unroll
                for (int j = 0; j < 4; ++j) acc[nt == 0 ? mt : mt][nt][q * 4 + j] = bv[j];
        }
}

// epilogue L1/L2: acc -> tanh fp16 image [256t][256B] (XOR swz) -> h frag tiles
__device__ __forceinline__ void epi_h(char* img, const f32x16 acc[2][2],
                                      _Float16* __restrict__ h, int Tt, int p,
                                      int wave, int wf, int wt, int lane,
                                      int r2, int hi) {
    #pragma unroll
    for (int mt = 0; mt < 2; ++mt)
        #pragma unroll
        for (int nt = 0; nt < 2; ++nt) {
            int t = wt * 64 + nt * 32 + r2;
            #pragma unroll
            for (int q = 0; q < 4; ++q) {
                int floc = wf * 64 + mt * 32 + q * 8 + hi * 4;
                half4v hv;
                #pragma unroll
                for (int j = 0; j < 4; ++j)
                    hv[j] = (_Float16)tanh_half(acc[mt][nt][q * 4 + j]);
                *(half4v*)(img + t * 256 + ((floc * 2) ^ ((t & 7) << 4))) = hv;
            }
        }
    lgkm0_bar();
    #pragma unroll
    for (int r = 0; r < 8; ++r) {
        int fid = wave * 8 + r;                 // 64 frags: [s2q4][kc2][tt8]
        int s2q = fid >> 4, kc = (fid >> 3) & 1, tt = fid & 7;
        int t = tt * 32 + (lane & 31);
        int floc = s2q * 32 + kc * 16 + (lane >> 5) * 8;
        uint4 v = *(const uint4*)(img + t * 256 + ((floc * 2) ^ ((t & 7) << 4)));
        char* dst = (char*)h + ((size_t)(p * 4 + s2q) * 512 + Tt) * 16384
                    + (kc * 8 + tt) * 1024 + lane * 16;
        *(uint4*)dst = v;
    }
}

// ---------------- L1: words (fp32, reg-staged) ----------------
__global__ __launch_bounds__(512, 4) void enc1_kernel(
    const float* __restrict__ words, const _Float16* __restrict__ F1,
    const float* __restrict__ b1s, _Float16* __restrict__ h1) {
    __shared__ __align__(16) char smem[65536];  // wbuf 2x8K @0 | abuf 2x16K @16384; epi image 64K

    const int tid = threadIdx.x;
    const int lane = tid & 63, wave = tid >> 6;
    const int r2 = lane & 31, hi = lane >> 5;
    const int wf = wave >> 2, wt = wave & 3;
    const int b = blockIdx.x, xcd = b & 7, sl = b >> 3;   // grid 2048
    const int p = sl & 3, Tt = xcd * 64 + (sl >> 2);

    const char* F1b = (const char*)F1 + (size_t)p * 8 * 8192;
    auto stage_w = [&](int s) {
        gload_lds16(F1b + (size_t)s * 8192 + tid * 16,
                    smem + (s & 1) * 8192 + tid * 16);
    };
    const int t_l = tid >> 1, kh = tid & 1;
    const float* wrow = words + ((size_t)Tt * 256 + t_l) * 256 + kh * 16;
    float4 g[4];
    auto load_g = [&](int s) {
        const float4* src = (const float4*)(wrow + s * 32);
        #pragma unroll
        for (int c = 0; c < 4; ++c) g[c] = src[c];
    };
    auto write_g = [&](int s) {
        char* ab = smem + 16384 + (s & 1) * 16384;
        int base = (kh * 8 + (t_l >> 5)) * 1024 + (t_l & 31) * 16;
        #pragma unroll
        for (int h2 = 0; h2 < 2; ++h2) {
            half8v hv;
            hv[0] = (_Float16)g[2 * h2].x;     hv[1] = (_Float16)g[2 * h2].y;
            hv[2] = (_Float16)g[2 * h2].z;     hv[3] = (_Float16)g[2 * h2].w;
            hv[4] = (_Float16)g[2 * h2 + 1].x; hv[5] = (_Float16)g[2 * h2 + 1].y;
            hv[6] = (_Float16)g[2 * h2 + 1].z; hv[7] = (_Float16)g[2 * h2 + 1].w;
            *(half8v*)(ab + base + h2 * 512) = hv;
        }
    };

    f32x16 acc[2][2];
    init_acc(acc, b1s + p * 128, wf, hi);

    stage_w(0); load_g(0);
    asm volatile("s_waitcnt vmcnt(0)" ::: "memory");
    write_g(0);
    lgkm0_bar();

    #pragma unroll
    for (int s = 0; s < 8; ++s) {
        if (s < 7) { stage_w(s + 1); load_g(s + 1); }
        kstep_compute(smem + (s & 1) * 8192, smem + 16384 + (s & 1) * 16384,
                      wf, wt, lane, acc);
        if (s < 7) {
            vm0_bar();
            write_g(s + 1);
            lgkm0_bar();
        }
    }
    __builtin_amdgcn_s_barrier();
    epi_h(smem, acc, h1, Tt, p, wave, wf, wt, lane, r2, hi);
}

// ---------------- L2: h1 (frag-gloaded) ----------------
__global__ __launch_bounds__(512, 4) void enc2_kernel(
    const _Float16* __restrict__ h1, const _Float16* __restrict__ F2,
    const float* __restrict__ b2s, _Float16* __restrict__ h2) {
    __shared__ __align__(16) char smem[65536];

    const int tid = threadIdx.x;
    const int lane = tid & 63, wave = tid >> 6;
    const int r2 = lane & 31, hi = lane >> 5;
    const int wf = wave >> 2, wt = wave & 3;
    const int b = blockIdx.x, xcd = b & 7, sl = b >> 3;   // grid 2048
    const int p = sl & 3, Tt = xcd * 64 + (sl >> 2);

    const char* F2b = (const char*)F2 + (size_t)p * 16 * 8192;
    auto stage = [&](int s) {
        gload_lds16(F2b + (size_t)s * 8192 + tid * 16,
                    smem + (s & 1) * 8192 + tid * 16);
        const char* ga = (const char*)h1 + ((size_t)s * 512 + Tt) * 16384;
        char* la = smem + 16384 + (s & 1) * 16384;
        #pragma unroll
        for (int it = 0; it < 2; ++it) {
            int o = (it * 512 + tid) * 16;
            gload_lds16(ga + o, la + o);
        }
    };

    f32x16 acc[2][2];
    init_acc(acc, b2s + p * 128, wf, hi);

    stage(0);
    #pragma unroll
    for (int s = 0; s < 16; ++s) {
        vm0_bar();
        if (s < 15) stage(s + 1);
        kstep_compute(smem + (s & 1) * 8192, smem + 16384 + (s & 1) * 16384,
                      wf, wt, lane, acc);
    }
    __builtin_amdgcn_s_barrier();
    epi_h(smem, acc, h2, Tt, p, wave, wf, wt, lane, r2, hi);
}

// ---------------- L3: h2 -> enc (fused segment sum) ----------------
__global__ __launch_bounds__(512, 4) void enc3_kernel(
    const _Float16* __restrict__ h2, const _Float16* __restrict__ F3,
    const float* __restrict__ b3, const int* __restrict__ seg_ids,
    float* __restrict__ enc) {
    __shared__ __align__(16) char smem[66560];  // staging 48K; seg image [128t][520B]
    __shared__ int sseg[256];

    const int tid = threadIdx.x;
    const int lane = tid & 63, wave = tid >> 6;
    const int r2 = lane & 31, hi = lane >> 5;
    const int wf = wave >> 2, wt = wave & 3;
    const int b = blockIdx.x, xcd = b & 7, sl = b >> 3;   // grid 1024
    const int p = sl & 1, Tt = xcd * 64 + (sl >> 1);

    if (tid < 256) sseg[tid] = seg_ids[Tt * 256 + tid];

    const char* F3b = (const char*)F3 + (size_t)p * 16 * 8192;
    auto stage = [&](int s) {
        gload_lds16(F3b + (size_t)s * 8192 + tid * 16,
                    smem + (s & 1) * 8192 + tid * 16);
        const char* ga = (const char*)h2 + ((size_t)s * 512 + Tt) * 16384;
        char* la = smem + 16384 + (s & 1) * 16384;
        #pragma unroll
        for (int it = 0; it < 2; ++it) {
            int o = (it * 512 + tid) * 16;
            gload_lds16(ga + o, la + o);
        }
    };

    f32x16 acc[2][2];
    init_acc(acc, b3 + p * 128, wf, hi);

    stage(0);
    #pragma unroll
    for (int s = 0; s < 16; ++s) {
        vm0_bar();
        if (s < 15) stage(s + 1);
        kstep_compute(smem + (s & 1) * 8192, smem + 16384 + (s & 1) * 16384,
                      wf, wt, lane, acc);
    }
    __builtin_amdgcn_s_barrier();

    // segment sum: 2 t-half rounds, image [128 tl][520 B] f32 (bank-friendly)
    #pragma unroll
    for (int th = 0; th < 2; ++th) {
        if ((wt >> 1) == th) {
            #pragma unroll
            for (int mt = 0; mt < 2; ++mt)
                #pragma unroll
                for (int nt = 0; nt < 2; ++nt) {
                    int tl = (wt & 1) * 64 + nt * 32 + r2;
                    #pragma unroll
                    for (int q = 0; q < 4; ++q) {
                        int floc = wf * 64 + mt * 32 + q * 8 + hi * 4;
                        *(float2*)(smem + tl * 520 + floc * 4) =
                            make_float2(acc[mt][nt][q * 4 + 0], acc[mt][nt][q * 4 + 1]);
                        *(float2*)(smem + tl * 520 + floc * 4 + 8) =
                            make_float2(acc[mt][nt][q * 4 + 2], acc[mt][nt][q * 4 + 3]);
                    }
                }
        }
        lgkm0_bar();
        {
            int f = tid & 127, tq = tid >> 7;
            float a = 0.0f;
            int cur = sseg[th * 128 + tq * 32];
            for (int i = 0; i < 32; ++i) {
                float v = *(const float*)(smem + (tq * 32 + i) * 520 + f * 4);
                int sg = sseg[th * 128 + tq * 32 + i];
                if (sg != cur) { atomicAdd(&enc[cur * 256 + p * 128 + f], a); a = 0.0f; cur = sg; }
                a += v;
            }
            atomicAdd(&enc[cur * 256 + p * 128 + f], a);
        }
        __builtin_amdgcn_s_barrier();
    }
}

// ---------------- predictor (tiny, fp32) ----------------
__global__ __launch_bounds__(256) void pred_kernel(
    const float* __restrict__ enc,
    const float* __restrict__ P1, const float* __restrict__ pb1,
    const float* __restrict__ P2, const float* __restrict__ pb2,
    const float* __restrict__ P3, const float* __restrict__ pb3,
    float* __restrict__ out) {
    __shared__ float se[256];
    __shared__ float sp[512];
    __shared__ float red[256];
    const int tid = threadIdx.x, b = blockIdx.x;
    se[tid] = enc[b * 256 + tid];
    __syncthreads();
    float a0 = pb1[tid], a1 = pb1[tid + 256];
    for (int k = 0; k < 256; ++k) {
        float e = se[k];
        a0 = fmaf(e, P1[k * 512 + tid], a0);
        a1 = fmaf(e, P1[k * 512 + tid + 256], a1);
    }
    sp[tid] = tanhf(a0);
    sp[tid + 256] = tanhf(a1);
    __syncthreads();
    a0 = pb2[tid]; a1 = pb2[tid + 256];
    for (int k = 0; k < 512; ++k) {
        float p = sp[k];
        a0 = fmaf(p, P2[k * 512 + tid], a0);
        a1 = fmaf(p, P2[k * 512 + tid + 256], a1);
    }
    __syncthreads();
    sp[tid] = tanhf(a0);
    sp[tid + 256] = tanhf(a1);
    __syncthreads();
    int j = tid & 31, part = tid >> 5;
    float s = 0.0f;
    for (int k = part * 64; k < part * 64 + 64; ++k)
        s = fmaf(sp[k], P3[k * 32 + j], s);
    red[tid] = s;
    __syncthreads();
    if (tid < 128) red[tid] += red[tid + 128];
    __syncthreads();
    if (tid < 64) red[tid] += red[tid + 64];
    __syncthreads();
    if (tid < 32) out[b * 32 + tid] = red[tid] + red[tid + 32] + pb3[tid];
}

extern "C" void kernel_launch(void* const* d_in, const int* in_sizes, int n_in,
                              void* d_out, int out_size, void* d_ws, size_t ws_size,
                              hipStream_t stream) {
    const float* words = (const float*)d_in[0];
    const int* seg_ids = (const int*)d_in[1];
    const float* W1 = (const float*)d_in[2];
    const float* b1 = (const float*)d_in[3];
    const float* W2 = (const float*)d_in[4];
    const float* b2 = (const float*)d_in[5];
    const float* W3 = (const float*)d_in[6];
    const float* b3 = (const float*)d_in[7];
    const float* P1 = (const float*)d_in[8];
    const float* pb1 = (const float*)d_in[9];
    const float* P2 = (const float*)d_in[10];
    const float* pb2 = (const float*)d_in[11];
    const float* P3 = (const float*)d_in[12];
    const float* pb3 = (const float*)d_in[13];
    float* out = (float*)d_out;

    char* ws = (char*)d_ws;
    _Float16* F1 = (_Float16*)(ws);                  // 262144 B
    _Float16* F2 = (_Float16*)(ws + 262144);         // 524288 B
    _Float16* F3 = (_Float16*)(ws + 786432);         // 262144 B
    float* b1s = (float*)(ws + 1048576);             // 2048 B
    float* b2s = (float*)(ws + 1050624);             // 2048 B
    float* enc = (float*)(ws + 1052672);             // 131072 B
    _Float16* h1 = (_Float16*)(ws + 1183744);        // 134217728 B
    _Float16* h2 = (_Float16*)(ws + 135401472);      // 134217728 B

    hipMemsetAsync(enc, 0, 128 * 256 * 4, stream);
    wt_kernel<<<256, 256, 0, stream>>>(W1, W2, W3, b1, b2, F1, F2, F3, b1s, b2s);
    enc1_kernel<<<2048, 512, 0, stream>>>(words, F1, b1s, h1);
    enc2_kernel<<<2048, 512, 0, stream>>>(h1, F2, b2s, h2);
    enc3_kernel<<<1024, 512, 0, stream>>>(h2, F3, b3, seg_ids, enc);
    pred_kernel<<<128, 256, 0, stream>>>(enc, P1, pb1, P2, pb2, P3, pb3, out);
}